// Round 16
// baseline (130.192 us; speedup 1.0000x reference)
//
#include <hip/hip_runtime.h>
#include <math.h>

#define BB 32
#define WW 100
#define FF 128
#define KS 7
#define ET 256   // 2F (temporal GAT embed)
#define EF 200   // 2W (feature GAT embed)

// b = blockIdx & 31 (b-minor): BB=32 ≡ 0 mod 8 XCDs -> all tiles of batch b
// land on one XCD; per-b panels are HBM-fetched once, then L2-served.

// K0: transpose the three weight tensors
__global__ void k_prep(const float* __restrict__ cw, const float* __restrict__ tlw,
                       const float* __restrict__ flw, float* __restrict__ wt,
                       float* __restrict__ tlwT, float* __restrict__ flwT) {
    int id = blockIdx.x * 256 + threadIdx.x;
    if (id < KS * FF * FF) {
        int o = id & (FF - 1);
        int r = id >> 7;
        int k = r % KS;
        int i = r / KS;
        wt[id] = cw[(o * FF + i) * KS + k];
    }
    if (id < ET * ET) {
        int e = id & (ET - 1);
        int d = id >> 8;
        tlwT[id] = tlw[e * ET + d];
    }
    if (id < EF * EF) {
        int e = id % EF;
        int d = id / EF;
        flwT[id] = flw[e * EF + d];
    }
}

// K1: Conv1d 'same' + relu, pos-encode fused. (R12 version)
#define CTW 10
#define NROW 16
#define XPAD 20
__global__ __launch_bounds__(512) void k_conv(const float* __restrict__ x,
                                              const float* __restrict__ wt,
                                              const float* __restrict__ cb,
                                              float* __restrict__ x2) {
    int b = blockIdx.x & 31;
    int tile = blockIdx.x >> 5;
    int w0 = tile * CTW;
    int tid = threadIdx.x;
    int o = tid & (FF - 1);
    int h = tid >> 7;
    __shared__ float xs[FF][XPAD];
    __shared__ float part[4][CTW][FF];
    for (int idx = tid; idx < NROW * FF; idx += 512) {
        int r = idx >> 7, f = idx & (FF - 1);
        int t = w0 - 3 + r;
        float v = 0.f;
        if ((unsigned)t < WW) {
            float div = __expf((float)f * (-9.210340371976184f / (float)FF));
            float arg = (float)t * div;
            v = x[(b * WW + t) * FF + f] + __sinf(arg) + __cosf(arg);
        }
        xs[f][r] = v;
    }
    __syncthreads();
    float acc[CTW];
#pragma unroll
    for (int t = 0; t < CTW; ++t) acc[t] = 0.f;
    const float* wbase = wt + (h * 32) * KS * FF + o;
#pragma unroll 2
    for (int il = 0; il < 32; ++il) {
        int i = h * 32 + il;
        float4 X0 = *(const float4*)&xs[i][0];
        float4 X1 = *(const float4*)&xs[i][4];
        float4 X2 = *(const float4*)&xs[i][8];
        float4 X3 = *(const float4*)&xs[i][12];
        float xr[16] = {X0.x, X0.y, X0.z, X0.w, X1.x, X1.y, X1.z, X1.w,
                        X2.x, X2.y, X2.z, X2.w, X3.x, X3.y, X3.z, X3.w};
        const float* wp = wbase + il * KS * FF;
#pragma unroll
        for (int k = 0; k < KS; ++k) {
            float wv = wp[k * FF];
#pragma unroll
            for (int t = 0; t < CTW; ++t) acc[t] += xr[t + k] * wv;
        }
    }
#pragma unroll
    for (int t = 0; t < CTW; ++t) part[h][t][o] = acc[t];
    __syncthreads();
    for (int idx = tid; idx < CTW * FF; idx += 512) {
        int t = idx >> 7, oo = idx & (FF - 1);
        float s = part[0][t][oo] + part[1][t][oo] + part[2][t][oo] +
                  part[3][t][oo] + cb[oo];
        x2[(b * WW + w0 + t) * FF + oo] = fmaxf(s, 0.f);
    }
}

// K2: temporal L/R GEMM. (R12 version)
__global__ __launch_bounds__(512) void k_lr_t(const float* __restrict__ x2,
                                              const float* __restrict__ tlwT,
                                              const float* __restrict__ tlb,
                                              float* __restrict__ LT,
                                              float* __restrict__ Rt) {
    int b = blockIdx.x & 31;
    int tile = blockIdx.x >> 5;
    int i0 = tile * 8;
    int tid = threadIdx.x;
    int e = tid & 255;
    int rh = tid >> 8;
    __shared__ float xs[8][FF];
    for (int idx = tid; idx < 8 * FF; idx += 512) {
        int r = idx >> 7, d = idx & (FF - 1);
        int row = i0 + r; if (row >= WW) row = WW - 1;
        xs[r][d] = x2[(b * WW + row) * FF + d];
    }
    __syncthreads();
    float aL[4] = {0, 0, 0, 0}, aR[4] = {0, 0, 0, 0};
    const float* wl = tlwT + e;
#pragma unroll 2
    for (int dc = 0; dc < 32; ++dc) {
        float xv[4][4];
#pragma unroll
        for (int r = 0; r < 4; ++r)
            *(float4*)xv[r] = *(const float4*)&xs[rh * 4 + r][dc * 4];
#pragma unroll
        for (int q = 0; q < 4; ++q) {
            int d = dc * 4 + q;
            float wL = wl[d * ET];
            float wR = wl[(FF + d) * ET];
#pragma unroll
            for (int r = 0; r < 4; ++r) {
                aL[r] += xv[r][q] * wL;
                aR[r] += xv[r][q] * wR;
            }
        }
    }
    int ibase = i0 + rh * 4;
    if (ibase < WW) {
        float lb = tlb[e];
        float o0[4];
#pragma unroll
        for (int r = 0; r < 4; ++r) o0[r] = aL[r] + lb;
        *(float4*)&LT[(b * ET + e) * WW + ibase] = *(float4*)o0;
        *(float4*)&Rt[(b * ET + e) * WW + ibase] = *(float4*)aR;
    }
}

// K3: temporal attention. 4-queries/thread score (e-split 2-way) + 4-queries
// PV (row-split 2-way): LDS ops halved vs R12. Double-buffered staging kept.
__global__ __launch_bounds__(512) void k_att_t(const float* __restrict__ LT,
                                               const float* __restrict__ Rt,
                                               const float* __restrict__ ta,
                                               const float* __restrict__ tbias,
                                               const float* __restrict__ x2,
                                               float* __restrict__ x3T) {
    int b = blockIdx.x & 31;
    int tile = blockIdx.x >> 5;   // 0..12
    int i0 = tile * 8;
    int tid = threadIdx.x;
    int j = tid & 127;
    int u = tid >> 7;             // 0..3
    int qh = u & 1;               // query quad
    int eh = u >> 1;              // e half (score) / row half (PV)
    __shared__ float Rs[2][32][FF];
    __shared__ float Ls[2][32][8];
    __shared__ float tas[ET];
    __shared__ float sacc[8][FF];     // cross-group partial accumulator
    __shared__ float attQT[FF][8];    // [key j][query]
    __shared__ float redA[8][4], redB[8][4];
    if (tid < ET) tas[tid] = ta[tid];

    float rv[8];
    float lvr = 0.f;
    {
        const float* Rb = Rt + (b * ET) * WW;
#pragma unroll
        for (int it = 0; it < 8; ++it) {
            int idx = tid + it * 512;
            int er = idx >> 7, w = idx & 127;
            rv[it] = (w < WW) ? Rb[er * WW + w] : 0.f;
        }
        if (tid < 256) {
            int er = tid >> 3, qq = tid & 7;
            int row = i0 + qq; if (row >= WW) row = WW - 1;
            lvr = LT[(b * ET + er) * WW + row];
        }
    }
#pragma unroll
    for (int it = 0; it < 8; ++it) {
        int idx = tid + it * 512;
        Rs[0][idx >> 7][idx & 127] = rv[it];
    }
    if (tid < 256) Ls[0][tid >> 3][tid & 7] = lvr;
    __syncthreads();

    float s[4] = {0.f, 0.f, 0.f, 0.f};
    for (int ch = 0; ch < 8; ++ch) {
        int buf = ch & 1;
        if (ch < 7) {
            int e0n = (ch + 1) * 32;
            const float* Rb = Rt + (b * ET + e0n) * WW;
#pragma unroll
            for (int it = 0; it < 8; ++it) {
                int idx = tid + it * 512;
                int er = idx >> 7, w = idx & 127;
                rv[it] = (w < WW) ? Rb[er * WW + w] : 0.f;
            }
            if (tid < 256) {
                int er = tid >> 3, qq = tid & 7;
                int row = i0 + qq; if (row >= WW) row = WW - 1;
                lvr = LT[(b * ET + e0n + er) * WW + row];
            }
        }
        int e0 = ch * 32;
#pragma unroll
        for (int el = 0; el < 16; ++el) {
            int e = eh * 16 + el;
            float rj = Rs[buf][e][j];
            float ae = tas[e0 + e];
            float4 lv = *(const float4*)&Ls[buf][e][qh * 4];
            float v;
            v = lv.x + rj; v = fmaxf(v, 0.2f * v); s[0] += v * ae;
            v = lv.y + rj; v = fmaxf(v, 0.2f * v); s[1] += v * ae;
            v = lv.z + rj; v = fmaxf(v, 0.2f * v); s[2] += v * ae;
            v = lv.w + rj; v = fmaxf(v, 0.2f * v); s[3] += v * ae;
        }
        if (ch < 7) {
#pragma unroll
            for (int it = 0; it < 8; ++it) {
                int idx = tid + it * 512;
                Rs[buf ^ 1][idx >> 7][idx & 127] = rv[it];
            }
            if (tid < 256) Ls[buf ^ 1][tid >> 3][tid & 7] = lvr;
        }
        __syncthreads();
    }
    // combine e-halves
    if (eh == 1) {
#pragma unroll
        for (int c = 0; c < 4; ++c) sacc[qh * 4 + c][j] = s[c];
    }
    __syncthreads();
    float ej[4], p[4];
    if (eh == 0) {
#pragma unroll
        for (int c = 0; c < 4; ++c) {
            int i = i0 + qh * 4 + c;
            float v = s[c] + sacc[qh * 4 + c][j];
            v += (j < WW && i < WW) ? tbias[i * WW + j] : 0.f;
            ej[c] = (j < WW && i < WW) ? v : -1e30f;
        }
    } else {
#pragma unroll
        for (int c = 0; c < 4; ++c) ej[c] = -1e30f;
    }
    float m[4] = {ej[0], ej[1], ej[2], ej[3]};
#pragma unroll
    for (int off = 32; off > 0; off >>= 1) {
#pragma unroll
        for (int c = 0; c < 4; ++c) m[c] = fmaxf(m[c], __shfl_xor(m[c], off));
    }
    int wv = tid >> 6;
    if ((tid & 63) == 0) {
#pragma unroll
        for (int c = 0; c < 4; ++c) redA[wv][c] = m[c];
    }
    __syncthreads();
    float ps[4];
#pragma unroll
    for (int c = 0; c < 4; ++c) {
        float mx = fmaxf(redA[wv][c], redA[wv ^ 1][c]);
        p[c] = (eh == 0 && j < WW) ? __expf(ej[c] - mx) : 0.f;
        ps[c] = p[c];
    }
#pragma unroll
    for (int off = 32; off > 0; off >>= 1) {
#pragma unroll
        for (int c = 0; c < 4; ++c) ps[c] += __shfl_xor(ps[c], off);
    }
    if ((tid & 63) == 0) {
#pragma unroll
        for (int c = 0; c < 4; ++c) redB[wv][c] = ps[c];
    }
    __syncthreads();
    if (eh == 0) {
#pragma unroll
        for (int c = 0; c < 4; ++c) {
            float inv = 1.f / (redB[wv][c] + redB[wv ^ 1][c]);
            attQT[j][qh * 4 + c] = p[c] * inv;   // j>=WW -> 0
        }
    }

    // PV: 4 chunks of 32 rows; u = (qq, rh); 4 queries via one b128 broadcast.
    int d = j, qq = qh, rh = eh;
    float pv[4] = {0.f, 0.f, 0.f, 0.f};
#pragma unroll
    for (int it = 0; it < 8; ++it) {
        int idx = tid + it * 512;
        int r = idx >> 7, f = idx & 127;
        rv[it] = (r < WW) ? x2[(b * WW + r) * FF + f] : 0.f;
    }
    __syncthreads();        // attQT visible; Rs free
#pragma unroll
    for (int it = 0; it < 8; ++it) {
        int idx = tid + it * 512;
        Rs[0][idx >> 7][idx & 127] = rv[it];
    }
    __syncthreads();
    for (int jc = 0; jc < 4; ++jc) {
        int buf = jc & 1;
        if (jc < 3) {
            int r0 = (jc + 1) * 32;
#pragma unroll
            for (int it = 0; it < 8; ++it) {
                int idx = tid + it * 512;
                int r = idx >> 7, f = idx & 127;
                int row = r0 + r;
                rv[it] = (row < WW) ? x2[(b * WW + row) * FF + f] : 0.f;
            }
        }
#pragma unroll
        for (int rr = 0; rr < 16; ++rr) {
            int r = rh * 16 + rr;
            float xv = Rs[buf][r][d];
            float4 av = *(const float4*)&attQT[jc * 32 + r][qq * 4];
            pv[0] += av.x * xv; pv[1] += av.y * xv;
            pv[2] += av.z * xv; pv[3] += av.w * xv;
        }
        if (jc < 3) {
#pragma unroll
            for (int it = 0; it < 8; ++it) {
                int idx = tid + it * 512;
                Rs[buf ^ 1][idx >> 7][idx & 127] = rv[it];
            }
        }
        __syncthreads();
    }
    if (rh == 1) {
#pragma unroll
        for (int c = 0; c < 4; ++c) sacc[qq * 4 + c][d] = pv[c];
    }
    __syncthreads();
    if (rh == 0) {
        float o0[4];
#pragma unroll
        for (int c = 0; c < 4; ++c) o0[c] = tanhf(pv[c] + sacc[qq * 4 + c][d]);
        if (i0 + qq * 4 < WW)
            *(float4*)&x3T[(b * FF + d) * WW + i0 + qq * 4] = *(float4*)o0;
    }
}

// K4: feature L/R GEMM. (unchanged)
__global__ __launch_bounds__(512) void k_lr_f(const float* __restrict__ x3T,
                                              const float* __restrict__ flwT,
                                              const float* __restrict__ flb,
                                              float* __restrict__ LfT,
                                              float* __restrict__ RfT) {
    int b = blockIdx.x & 31;
    int tile = blockIdx.x >> 5;
    int f0 = tile * 8;
    int tid = threadIdx.x;
    int e = tid & 255;
    int rh = tid >> 8;
    __shared__ float xs[8][WW];
    for (int idx = tid; idx < 8 * WW; idx += 512) {
        int r = idx / WW, d = idx % WW;
        xs[r][d] = x3T[(b * FF + f0 + r) * WW + d];
    }
    __syncthreads();
    if (e < EF) {
        float aL[4] = {0, 0, 0, 0}, aR[4] = {0, 0, 0, 0};
        const float* wl = flwT + e;
#pragma unroll 2
        for (int dc = 0; dc < 25; ++dc) {
            float xv[4][4];
#pragma unroll
            for (int r = 0; r < 4; ++r)
                *(float4*)xv[r] = *(const float4*)&xs[rh * 4 + r][dc * 4];
#pragma unroll
            for (int q = 0; q < 4; ++q) {
                int d = dc * 4 + q;
                float wL = wl[d * EF];
                float wR = wl[(WW + d) * EF];
#pragma unroll
                for (int r = 0; r < 4; ++r) {
                    aL[r] += xv[r][q] * wL;
                    aR[r] += xv[r][q] * wR;
                }
            }
        }
        float lb = flb[e];
        float o0[4];
#pragma unroll
        for (int r = 0; r < 4; ++r) o0[r] = aL[r] + lb;
        int fbase = f0 + rh * 4;
        *(float4*)&LfT[(b * EF + e) * FF + fbase] = *(float4*)o0;
        *(float4*)&RfT[(b * EF + e) * FF + fbase] = *(float4*)aR;
    }
}

// K5: feature attention, same 4-query restructure; fused tj reduction.
__global__ __launch_bounds__(512) void k_att_f(const float* __restrict__ LfT,
                                               const float* __restrict__ RfT,
                                               const float* __restrict__ fa,
                                               const float* __restrict__ fbias,
                                               const float* __restrict__ x3T,
                                               const float* __restrict__ fcw,
                                               float* __restrict__ tj) {
    int b = blockIdx.x & 31;
    int tile = blockIdx.x >> 5;   // 0..15
    int f0 = tile * 8;
    int tid = threadIdx.x;
    int j = tid & 127;
    int u = tid >> 7;
    int qh = u & 1;
    int eh = u >> 1;
    __shared__ float Rs[2][40][FF];
    __shared__ float Ls[2][40][8];
    __shared__ float fas[EF];
    __shared__ float sacc[8][FF];
    __shared__ float attQT[FF][8];
    __shared__ float redA[8][4], redB[8][4], redT[8][4];
    if (tid < EF) fas[tid] = fa[tid];

    float rv[10];
    float lvr = 0.f;
    {
        const float* Rb = RfT + (b * EF) * FF;
#pragma unroll
        for (int it = 0; it < 10; ++it) {
            int idx = tid + it * 512;
            rv[it] = Rb[idx];
        }
        if (tid < 320) {
            int er = tid >> 3, qq = tid & 7;
            lvr = LfT[(b * EF + er) * FF + f0 + qq];
        }
    }
#pragma unroll
    for (int it = 0; it < 10; ++it) {
        int idx = tid + it * 512;
        Rs[0][idx >> 7][idx & 127] = rv[it];
    }
    if (tid < 320) Ls[0][tid >> 3][tid & 7] = lvr;
    __syncthreads();

    float s[4] = {0.f, 0.f, 0.f, 0.f};
    for (int ch = 0; ch < 5; ++ch) {
        int buf = ch & 1;
        if (ch < 4) {
            int e0n = (ch + 1) * 40;
            const float* Rb = RfT + (b * EF + e0n) * FF;
#pragma unroll
            for (int it = 0; it < 10; ++it) {
                int idx = tid + it * 512;
                rv[it] = Rb[idx];
            }
            if (tid < 320) {
                int er = tid >> 3, qq = tid & 7;
                lvr = LfT[(b * EF + e0n + er) * FF + f0 + qq];
            }
        }
        int e0 = ch * 40;
#pragma unroll
        for (int el = 0; el < 20; ++el) {
            int e = eh * 20 + el;
            float rj = Rs[buf][e][j];
            float ae = fas[e0 + e];
            float4 lv = *(const float4*)&Ls[buf][e][qh * 4];
            float v;
            v = lv.x + rj; v = fmaxf(v, 0.2f * v); s[0] += v * ae;
            v = lv.y + rj; v = fmaxf(v, 0.2f * v); s[1] += v * ae;
            v = lv.z + rj; v = fmaxf(v, 0.2f * v); s[2] += v * ae;
            v = lv.w + rj; v = fmaxf(v, 0.2f * v); s[3] += v * ae;
        }
        if (ch < 4) {
#pragma unroll
            for (int it = 0; it < 10; ++it) {
                int idx = tid + it * 512;
                Rs[buf ^ 1][idx >> 7][idx & 127] = rv[it];
            }
            if (tid < 320) Ls[buf ^ 1][tid >> 3][tid & 7] = lvr;
        }
        __syncthreads();
    }
    if (eh == 1) {
#pragma unroll
        for (int c = 0; c < 4; ++c) sacc[qh * 4 + c][j] = s[c];
    }
    __syncthreads();
    float ej[4], p[4];
    if (eh == 0) {
#pragma unroll
        for (int c = 0; c < 4; ++c)
            ej[c] = s[c] + sacc[qh * 4 + c][j] + fbias[(f0 + qh * 4 + c) * FF + j];
    } else {
#pragma unroll
        for (int c = 0; c < 4; ++c) ej[c] = -1e30f;
    }
    float m[4] = {ej[0], ej[1], ej[2], ej[3]};
#pragma unroll
    for (int off = 32; off > 0; off >>= 1) {
#pragma unroll
        for (int c = 0; c < 4; ++c) m[c] = fmaxf(m[c], __shfl_xor(m[c], off));
    }
    int wv = tid >> 6;
    if ((tid & 63) == 0) {
#pragma unroll
        for (int c = 0; c < 4; ++c) redA[wv][c] = m[c];
    }
    __syncthreads();
    float ps[4];
#pragma unroll
    for (int c = 0; c < 4; ++c) {
        float mx = fmaxf(redA[wv][c], redA[wv ^ 1][c]);
        p[c] = (eh == 0) ? __expf(ej[c] - mx) : 0.f;
        ps[c] = p[c];
    }
#pragma unroll
    for (int off = 32; off > 0; off >>= 1) {
#pragma unroll
        for (int c = 0; c < 4; ++c) ps[c] += __shfl_xor(ps[c], off);
    }
    if ((tid & 63) == 0) {
#pragma unroll
        for (int c = 0; c < 4; ++c) redB[wv][c] = ps[c];
    }
    __syncthreads();
    if (eh == 0) {
#pragma unroll
        for (int c = 0; c < 4; ++c) {
            float inv = 1.f / (redB[wv][c] + redB[wv ^ 1][c]);
            attQT[j][qh * 4 + c] = p[c] * inv;
        }
    }

    // PV: 4 chunks of 32 rows of x3T; u = (qq, rh).
    int w = j, qq = qh, rh = eh;
    float pv[4] = {0.f, 0.f, 0.f, 0.f};
#pragma unroll
    for (int it = 0; it < 8; ++it) {
        int idx = tid + it * 512;
        int r = idx >> 7, ww = idx & 127;
        rv[it] = (ww < WW) ? x3T[(b * FF + r) * WW + ww] : 0.f;
    }
    __syncthreads();
#pragma unroll
    for (int it = 0; it < 8; ++it) {
        int idx = tid + it * 512;
        Rs[0][idx >> 7][idx & 127] = rv[it];
    }
    __syncthreads();
    for (int jc = 0; jc < 4; ++jc) {
        int buf = jc & 1;
        if (jc < 3) {
            int r0 = (jc + 1) * 32;
#pragma unroll
            for (int it = 0; it < 8; ++it) {
                int idx = tid + it * 512;
                int r = idx >> 7, ww = idx & 127;
                rv[it] = (ww < WW) ? x3T[(b * FF + r0 + r) * WW + ww] : 0.f;
            }
        }
#pragma unroll
        for (int rr = 0; rr < 16; ++rr) {
            int r = rh * 16 + rr;
            float xv = Rs[buf][r][w];
            float4 av = *(const float4*)&attQT[jc * 32 + r][qq * 4];
            pv[0] += av.x * xv; pv[1] += av.y * xv;
            pv[2] += av.z * xv; pv[3] += av.w * xv;
        }
        if (jc < 3) {
#pragma unroll
            for (int it = 0; it < 8; ++it) {
                int idx = tid + it * 512;
                Rs[buf ^ 1][idx >> 7][idx & 127] = rv[it];
            }
        }
        __syncthreads();
    }
    if (rh == 1) {
#pragma unroll
        for (int c = 0; c < 4; ++c) sacc[qq * 4 + c][w] = pv[c];
    }
    __syncthreads();
    if (rh == 0) {
        bool wok = (w < WW);
        float fcv = wok ? fcw[w] : 0.f;
        float tv[4];
#pragma unroll
        for (int c = 0; c < 4; ++c)
            tv[c] = tanhf(pv[c] + sacc[qq * 4 + c][w]) * fcv;
#pragma unroll
        for (int off = 32; off > 0; off >>= 1) {
#pragma unroll
            for (int c = 0; c < 4; ++c) tv[c] += __shfl_xor(tv[c], off);
        }
        if ((tid & 63) == 0) {
#pragma unroll
            for (int c = 0; c < 4; ++c) redT[wv][c] = tv[c];
        }
    }
    __syncthreads();
    if (tid < 8) {
        int q = tid, qqo = q >> 2, c = q & 3;
        tj[b * FF + f0 + q] = redT[qqo * 2][c] + redT[qqo * 2 + 1][c];
    }
}

// K6: out[b,f] = tanh(sum_j cos(f,j)*tj[b,j] + fcb). (R12 version)
__global__ __launch_bounds__(128) void k_fc(const float* __restrict__ tjg,
                                            const float* __restrict__ emb,
                                            const float* __restrict__ fcb,
                                            float* __restrict__ out) {
    int b = blockIdx.x;
    int f = threadIdx.x;
    __shared__ float en[FF][12];
    __shared__ float tjs[FF];
    {
        float4 e0 = *(const float4*)&emb[f * 8];
        float4 e1 = *(const float4*)&emb[f * 8 + 4];
        float n = e0.x*e0.x + e0.y*e0.y + e0.z*e0.z + e0.w*e0.w +
                  e1.x*e1.x + e1.y*e1.y + e1.z*e1.z + e1.w*e1.w;
        float rin = rsqrtf(n);
        float4 a = make_float4(e0.x*rin, e0.y*rin, e0.z*rin, e0.w*rin);
        float4 c = make_float4(e1.x*rin, e1.y*rin, e1.z*rin, e1.w*rin);
        *(float4*)&en[f][0] = a;
        *(float4*)&en[f][4] = c;
        tjs[f] = tjg[b * FF + f];
    }
    __syncthreads();
    float er[8];
#pragma unroll
    for (int k = 0; k < 8; ++k) er[k] = en[f][k];
    float acc = fcb[0];
    for (int jj = 0; jj < FF; ++jj) {
        float4 a = *(const float4*)&en[jj][0];
        float4 c = *(const float4*)&en[jj][4];
        float d8 = er[0]*a.x + er[1]*a.y + er[2]*a.z + er[3]*a.w +
                   er[4]*c.x + er[5]*c.y + er[6]*c.z + er[7]*c.w;
        acc += d8 * tjs[jj];
    }
    out[b * FF + f] = tanhf(acc);
}

extern "C" void kernel_launch(void* const* d_in, const int* in_sizes, int n_in,
                              void* d_out, int out_size, void* d_ws, size_t ws_size,
                              hipStream_t stream) {
    const float* x     = (const float*)d_in[0];
    const float* cw    = (const float*)d_in[1];
    const float* cb    = (const float*)d_in[2];
    const float* tlw   = (const float*)d_in[3];
    const float* tlb   = (const float*)d_in[4];
    const float* ta    = (const float*)d_in[5];
    const float* tbias = (const float*)d_in[6];
    const float* flw   = (const float*)d_in[7];
    const float* flb   = (const float*)d_in[8];
    const float* fa    = (const float*)d_in[9];
    const float* fbias = (const float*)d_in[10];
    const float* emb   = (const float*)d_in[11];
    const float* fcw   = (const float*)d_in[12];
    const float* fcb   = (const float*)d_in[13];
    float* out = (float*)d_out;
    float* ws = (float*)d_ws;

    float* x2   = ws + 409600;
    float* x3T  = ws + 819200;
    float* LT   = ws + 1228800;   // reused as LfT
    float* Rt   = ws + 2048000;   // reused as RfT
    float* tj   = ws + 2867200;
    float* wt   = ws + 3297280;
    float* tlwT = ws + 3411968;
    float* flwT = ws + 3477504;

    k_prep<<<448, 256, 0, stream>>>(cw, tlw, flw, wt, tlwT, flwT);
    k_conv<<<BB * 10, 512, 0, stream>>>(x, wt, cb, x2);
    k_lr_t<<<BB * 13, 512, 0, stream>>>(x2, tlwT, tlb, LT, Rt);
    k_att_t<<<BB * 13, 512, 0, stream>>>(LT, Rt, ta, tbias, x2, x3T);
    k_lr_f<<<BB * 16, 512, 0, stream>>>(x3T, flwT, flb, LT, Rt);
    k_att_f<<<BB * 16, 512, 0, stream>>>(LT, Rt, fa, fbias, x3T, fcw, tj);
    k_fc<<<BB, 128, 0, stream>>>(tj, emb, fcb, out);
}

// Round 17
// 129.167 us; speedup vs baseline: 1.0079x; 1.0079x over previous
//
#include <hip/hip_runtime.h>
#include <math.h>

#define BB 32
#define WW 100
#define FF 128
#define KS 7
#define ET 256   // 2F (temporal GAT embed)
#define EF 200   // 2W (feature GAT embed)

// b = blockIdx & 31 (b-minor): BB=32 ≡ 0 mod 8 XCDs -> all tiles of batch b
// land on one XCD; per-b panels are HBM-fetched once, then L2-served.

// K0: transpose the three weight tensors
__global__ void k_prep(const float* __restrict__ cw, const float* __restrict__ tlw,
                       const float* __restrict__ flw, float* __restrict__ wt,
                       float* __restrict__ tlwT, float* __restrict__ flwT) {
    int id = blockIdx.x * 256 + threadIdx.x;
    if (id < KS * FF * FF) {
        int o = id & (FF - 1);
        int r = id >> 7;
        int k = r % KS;
        int i = r / KS;
        wt[id] = cw[(o * FF + i) * KS + k];
    }
    if (id < ET * ET) {
        int e = id & (ET - 1);
        int d = id >> 8;
        tlwT[id] = tlw[e * ET + d];
    }
    if (id < EF * EF) {
        int e = id % EF;
        int d = id / EF;
        flwT[id] = flw[e * EF + d];
    }
}

// K1: Conv1d 'same' + relu, pos-encode fused. (R12 version)
#define CTW 10
#define NROW 16
#define XPAD 20
__global__ __launch_bounds__(512) void k_conv(const float* __restrict__ x,
                                              const float* __restrict__ wt,
                                              const float* __restrict__ cb,
                                              float* __restrict__ x2) {
    int b = blockIdx.x & 31;
    int tile = blockIdx.x >> 5;
    int w0 = tile * CTW;
    int tid = threadIdx.x;
    int o = tid & (FF - 1);
    int h = tid >> 7;
    __shared__ float xs[FF][XPAD];
    __shared__ float part[4][CTW][FF];
    for (int idx = tid; idx < NROW * FF; idx += 512) {
        int r = idx >> 7, f = idx & (FF - 1);
        int t = w0 - 3 + r;
        float v = 0.f;
        if ((unsigned)t < WW) {
            float div = __expf((float)f * (-9.210340371976184f / (float)FF));
            float arg = (float)t * div;
            v = x[(b * WW + t) * FF + f] + __sinf(arg) + __cosf(arg);
        }
        xs[f][r] = v;
    }
    __syncthreads();
    float acc[CTW];
#pragma unroll
    for (int t = 0; t < CTW; ++t) acc[t] = 0.f;
    const float* wbase = wt + (h * 32) * KS * FF + o;
#pragma unroll 2
    for (int il = 0; il < 32; ++il) {
        int i = h * 32 + il;
        float4 X0 = *(const float4*)&xs[i][0];
        float4 X1 = *(const float4*)&xs[i][4];
        float4 X2 = *(const float4*)&xs[i][8];
        float4 X3 = *(const float4*)&xs[i][12];
        float xr[16] = {X0.x, X0.y, X0.z, X0.w, X1.x, X1.y, X1.z, X1.w,
                        X2.x, X2.y, X2.z, X2.w, X3.x, X3.y, X3.z, X3.w};
        const float* wp = wbase + il * KS * FF;
#pragma unroll
        for (int k = 0; k < KS; ++k) {
            float wv = wp[k * FF];
#pragma unroll
            for (int t = 0; t < CTW; ++t) acc[t] += xr[t + k] * wv;
        }
    }
#pragma unroll
    for (int t = 0; t < CTW; ++t) part[h][t][o] = acc[t];
    __syncthreads();
    for (int idx = tid; idx < CTW * FF; idx += 512) {
        int t = idx >> 7, oo = idx & (FF - 1);
        float s = part[0][t][oo] + part[1][t][oo] + part[2][t][oo] +
                  part[3][t][oo] + cb[oo];
        x2[(b * WW + w0 + t) * FF + oo] = fmaxf(s, 0.f);
    }
}

// K2: temporal L/R GEMM. (R12 version)
__global__ __launch_bounds__(512) void k_lr_t(const float* __restrict__ x2,
                                              const float* __restrict__ tlwT,
                                              const float* __restrict__ tlb,
                                              float* __restrict__ LT,
                                              float* __restrict__ Rt) {
    int b = blockIdx.x & 31;
    int tile = blockIdx.x >> 5;
    int i0 = tile * 8;
    int tid = threadIdx.x;
    int e = tid & 255;
    int rh = tid >> 8;
    __shared__ float xs[8][FF];
    for (int idx = tid; idx < 8 * FF; idx += 512) {
        int r = idx >> 7, d = idx & (FF - 1);
        int row = i0 + r; if (row >= WW) row = WW - 1;
        xs[r][d] = x2[(b * WW + row) * FF + d];
    }
    __syncthreads();
    float aL[4] = {0, 0, 0, 0}, aR[4] = {0, 0, 0, 0};
    const float* wl = tlwT + e;
#pragma unroll 2
    for (int dc = 0; dc < 32; ++dc) {
        float xv[4][4];
#pragma unroll
        for (int r = 0; r < 4; ++r)
            *(float4*)xv[r] = *(const float4*)&xs[rh * 4 + r][dc * 4];
#pragma unroll
        for (int q = 0; q < 4; ++q) {
            int d = dc * 4 + q;
            float wL = wl[d * ET];
            float wR = wl[(FF + d) * ET];
#pragma unroll
            for (int r = 0; r < 4; ++r) {
                aL[r] += xv[r][q] * wL;
                aR[r] += xv[r][q] * wR;
            }
        }
    }
    int ibase = i0 + rh * 4;
    if (ibase < WW) {
        float lb = tlb[e];
        float o0[4];
#pragma unroll
        for (int r = 0; r < 4; ++r) o0[r] = aL[r] + lb;
        *(float4*)&LT[(b * ET + e) * WW + ibase] = *(float4*)o0;
        *(float4*)&Rt[(b * ET + e) * WW + ibase] = *(float4*)aR;
    }
}

// K3: temporal attention. R12 structure; L/ta reads converted to SCALAR
// (SMEM) loads via readfirstlane-forced uniform addresses -> score-loop LDS
// ops 3x -> 1x, Ls/tas staging removed.
__global__ __launch_bounds__(512) void k_att_t(const float* __restrict__ LT,
                                               const float* __restrict__ Rt,
                                               const float* __restrict__ ta,
                                               const float* __restrict__ tbias,
                                               const float* __restrict__ x2,
                                               float* __restrict__ x3T) {
    int b = blockIdx.x & 31;
    int tile = blockIdx.x >> 5;   // 0..12
    int i0 = tile * 8;
    int tid = threadIdx.x;
    int j = tid & 127, g = tid >> 7;
    __shared__ float Rs[2][32][FF];
    __shared__ float attQ[8][FF];
    __shared__ float ob[8][FF];
    __shared__ float redA[8][2], redB[8][2];

    // wave-uniform L row addresses (forced scalar)
    int gg = __builtin_amdgcn_readfirstlane(g);
    int row0 = i0 + gg * 2;     if (row0 >= WW) row0 = WW - 1;
    int row1 = i0 + gg * 2 + 1; if (row1 >= WW) row1 = WW - 1;
    const float* Lb = LT + (size_t)(b * ET) * WW;

    float rv[8];
    {
        const float* Rb = Rt + (b * ET) * WW;
#pragma unroll
        for (int it = 0; it < 8; ++it) {
            int idx = tid + it * 512;
            int er = idx >> 7, w = idx & 127;
            rv[it] = (w < WW) ? Rb[er * WW + w] : 0.f;
        }
    }
#pragma unroll
    for (int it = 0; it < 8; ++it) {
        int idx = tid + it * 512;
        Rs[0][idx >> 7][idx & 127] = rv[it];
    }
    __syncthreads();

    float s0 = 0.f, s1 = 0.f;
    for (int ch = 0; ch < 8; ++ch) {
        int buf = ch & 1;
        if (ch < 7) {
            int e0n = (ch + 1) * 32;
            const float* Rb = Rt + (b * ET + e0n) * WW;
#pragma unroll
            for (int it = 0; it < 8; ++it) {
                int idx = tid + it * 512;
                int er = idx >> 7, w = idx & 127;
                rv[it] = (w < WW) ? Rb[er * WW + w] : 0.f;
            }
        }
        int e0 = ch * 32;
#pragma unroll 8
        for (int e = 0; e < 32; ++e) {
            float rj = Rs[buf][e][j];
            float ae = ta[e0 + e];                       // scalar (uniform)
            float l0 = Lb[(e0 + e) * WW + row0];         // scalar (uniform)
            float l1 = Lb[(e0 + e) * WW + row1];         // scalar (uniform)
            float v;
            v = l0 + rj; v = fmaxf(v, 0.2f * v); s0 += v * ae;
            v = l1 + rj; v = fmaxf(v, 0.2f * v); s1 += v * ae;
        }
        if (ch < 7) {
#pragma unroll
            for (int it = 0; it < 8; ++it) {
                int idx = tid + it * 512;
                Rs[buf ^ 1][idx >> 7][idx & 127] = rv[it];
            }
        }
        __syncthreads();
    }

    float ej[2];
    {
        int iq = i0 + g * 2;
        float bv0 = (j < WW && iq < WW) ? tbias[iq * WW + j] : 0.f;
        float bv1 = (j < WW && iq + 1 < WW) ? tbias[(iq + 1) * WW + j] : 0.f;
        ej[0] = (j < WW && iq < WW) ? s0 + bv0 : -1e30f;
        ej[1] = (j < WW && iq + 1 < WW) ? s1 + bv1 : -1e30f;
    }
    float m[2] = {ej[0], ej[1]};
#pragma unroll
    for (int off = 32; off > 0; off >>= 1) {
#pragma unroll
        for (int ii = 0; ii < 2; ++ii) m[ii] = fmaxf(m[ii], __shfl_xor(m[ii], off));
    }
    int wv = tid >> 6;
    if ((tid & 63) == 0) { redA[wv][0] = m[0]; redA[wv][1] = m[1]; }
    __syncthreads();
    float p[2], ps[2];
#pragma unroll
    for (int ii = 0; ii < 2; ++ii) {
        float mx = fmaxf(redA[g * 2][ii], redA[g * 2 + 1][ii]);
        p[ii] = (j < WW) ? __expf(ej[ii] - mx) : 0.f;
        ps[ii] = p[ii];
    }
#pragma unroll
    for (int off = 32; off > 0; off >>= 1) {
#pragma unroll
        for (int ii = 0; ii < 2; ++ii) ps[ii] += __shfl_xor(ps[ii], off);
    }
    if ((tid & 63) == 0) { redB[wv][0] = ps[0]; redB[wv][1] = ps[1]; }
    __syncthreads();
#pragma unroll
    for (int ii = 0; ii < 2; ++ii) {
        float inv = 1.f / (redB[g * 2][ii] + redB[g * 2 + 1][ii]);
        attQ[g * 2 + ii][j] = p[ii] * inv;
    }

    int d = j, ph = g;
    float pv0 = 0.f, pv1 = 0.f;
#pragma unroll
    for (int it = 0; it < 8; ++it) {
        int idx = tid + it * 512;
        int r = idx >> 7, f = idx & 127;
        rv[it] = (r < WW) ? x2[(b * WW + r) * FF + f] : 0.f;
    }
    __syncthreads();
#pragma unroll
    for (int it = 0; it < 8; ++it) {
        int idx = tid + it * 512;
        Rs[0][idx >> 7][idx & 127] = rv[it];
    }
    __syncthreads();
    const float* a0 = attQ[ph * 2];
    const float* a1 = attQ[ph * 2 + 1];
    for (int jc = 0; jc < 4; ++jc) {
        int buf = jc & 1;
        if (jc < 3) {
            int r0 = (jc + 1) * 32;
#pragma unroll
            for (int it = 0; it < 8; ++it) {
                int idx = tid + it * 512;
                int r = idx >> 7, f = idx & 127;
                int row = r0 + r;
                rv[it] = (row < WW) ? x2[(b * WW + row) * FF + f] : 0.f;
            }
        }
#pragma unroll 8
        for (int r = 0; r < 32; ++r) {
            float xv = Rs[buf][r][d];
            int row = jc * 32 + r;
            pv0 += a0[row] * xv;
            pv1 += a1[row] * xv;
        }
        if (jc < 3) {
#pragma unroll
            for (int it = 0; it < 8; ++it) {
                int idx = tid + it * 512;
                Rs[buf ^ 1][idx >> 7][idx & 127] = rv[it];
            }
        }
        __syncthreads();
    }
    ob[ph * 2][d] = tanhf(pv0);
    ob[ph * 2 + 1][d] = tanhf(pv1);
    __syncthreads();
    if (tid < 256) {
        int f = tid >> 1, half = tid & 1;
        if (i0 + half * 4 < WW) {
            float4 v = make_float4(ob[half * 4][f], ob[half * 4 + 1][f],
                                   ob[half * 4 + 2][f], ob[half * 4 + 3][f]);
            *(float4*)&x3T[(b * FF + f) * WW + i0 + half * 4] = v;
        }
    }
}

// K4: feature L/R GEMM. (unchanged)
__global__ __launch_bounds__(512) void k_lr_f(const float* __restrict__ x3T,
                                              const float* __restrict__ flwT,
                                              const float* __restrict__ flb,
                                              float* __restrict__ LfT,
                                              float* __restrict__ RfT) {
    int b = blockIdx.x & 31;
    int tile = blockIdx.x >> 5;
    int f0 = tile * 8;
    int tid = threadIdx.x;
    int e = tid & 255;
    int rh = tid >> 8;
    __shared__ float xs[8][WW];
    for (int idx = tid; idx < 8 * WW; idx += 512) {
        int r = idx / WW, d = idx % WW;
        xs[r][d] = x3T[(b * FF + f0 + r) * WW + d];
    }
    __syncthreads();
    if (e < EF) {
        float aL[4] = {0, 0, 0, 0}, aR[4] = {0, 0, 0, 0};
        const float* wl = flwT + e;
#pragma unroll 2
        for (int dc = 0; dc < 25; ++dc) {
            float xv[4][4];
#pragma unroll
            for (int r = 0; r < 4; ++r)
                *(float4*)xv[r] = *(const float4*)&xs[rh * 4 + r][dc * 4];
#pragma unroll
            for (int q = 0; q < 4; ++q) {
                int d = dc * 4 + q;
                float wL = wl[d * EF];
                float wR = wl[(WW + d) * EF];
#pragma unroll
                for (int r = 0; r < 4; ++r) {
                    aL[r] += xv[r][q] * wL;
                    aR[r] += xv[r][q] * wR;
                }
            }
        }
        float lb = flb[e];
        float o0[4];
#pragma unroll
        for (int r = 0; r < 4; ++r) o0[r] = aL[r] + lb;
        int fbase = f0 + rh * 4;
        *(float4*)&LfT[(b * EF + e) * FF + fbase] = *(float4*)o0;
        *(float4*)&RfT[(b * EF + e) * FF + fbase] = *(float4*)aR;
    }
}

// K5: feature attention. R12 structure + scalar L/fa loads; fused tj reduce.
__global__ __launch_bounds__(512) void k_att_f(const float* __restrict__ LfT,
                                               const float* __restrict__ RfT,
                                               const float* __restrict__ fa,
                                               const float* __restrict__ fbias,
                                               const float* __restrict__ x3T,
                                               const float* __restrict__ fcw,
                                               float* __restrict__ tj) {
    int b = blockIdx.x & 31;
    int tile = blockIdx.x >> 5;   // 0..15
    int f0 = tile * 8;
    int tid = threadIdx.x;
    int j = tid & 127, g = tid >> 7;
    __shared__ float Rs[2][40][FF];
    __shared__ float attQ[8][FF];
    __shared__ float redA[8][2], redB[8][2], redT[8][2];

    int gg = __builtin_amdgcn_readfirstlane(g);
    int col0 = f0 + gg * 2;
    const float* Lb = LfT + (size_t)(b * EF) * FF;

    float rv[10];
    {
        const float* Rb = RfT + (b * EF) * FF;
#pragma unroll
        for (int it = 0; it < 10; ++it) {
            int idx = tid + it * 512;
            rv[it] = Rb[idx];
        }
    }
#pragma unroll
    for (int it = 0; it < 10; ++it) {
        int idx = tid + it * 512;
        Rs[0][idx >> 7][idx & 127] = rv[it];
    }
    __syncthreads();

    float s0 = 0.f, s1 = 0.f;
    for (int ch = 0; ch < 5; ++ch) {
        int buf = ch & 1;
        if (ch < 4) {
            int e0n = (ch + 1) * 40;
            const float* Rb = RfT + (b * EF + e0n) * FF;
#pragma unroll
            for (int it = 0; it < 10; ++it) {
                int idx = tid + it * 512;
                rv[it] = Rb[idx];
            }
        }
        int e0 = ch * 40;
#pragma unroll 8
        for (int e = 0; e < 40; ++e) {
            float rj = Rs[buf][e][j];
            float ae = fa[e0 + e];                        // scalar
            float l0 = Lb[(e0 + e) * FF + col0];          // scalar
            float l1 = Lb[(e0 + e) * FF + col0 + 1];      // scalar
            float v;
            v = l0 + rj; v = fmaxf(v, 0.2f * v); s0 += v * ae;
            v = l1 + rj; v = fmaxf(v, 0.2f * v); s1 += v * ae;
        }
        if (ch < 4) {
#pragma unroll
            for (int it = 0; it < 10; ++it) {
                int idx = tid + it * 512;
                Rs[buf ^ 1][idx >> 7][idx & 127] = rv[it];
            }
        }
        __syncthreads();
    }

    float ej[2] = {s0 + fbias[(f0 + g * 2) * FF + j],
                   s1 + fbias[(f0 + g * 2 + 1) * FF + j]};
    float m[2] = {ej[0], ej[1]};
#pragma unroll
    for (int off = 32; off > 0; off >>= 1) {
#pragma unroll
        for (int ii = 0; ii < 2; ++ii) m[ii] = fmaxf(m[ii], __shfl_xor(m[ii], off));
    }
    int wv = tid >> 6;
    if ((tid & 63) == 0) { redA[wv][0] = m[0]; redA[wv][1] = m[1]; }
    __syncthreads();
    float p[2], ps[2];
#pragma unroll
    for (int ii = 0; ii < 2; ++ii) {
        float mx = fmaxf(redA[g * 2][ii], redA[g * 2 + 1][ii]);
        p[ii] = __expf(ej[ii] - mx);
        ps[ii] = p[ii];
    }
#pragma unroll
    for (int off = 32; off > 0; off >>= 1) {
#pragma unroll
        for (int ii = 0; ii < 2; ++ii) ps[ii] += __shfl_xor(ps[ii], off);
    }
    if ((tid & 63) == 0) { redB[wv][0] = ps[0]; redB[wv][1] = ps[1]; }
    __syncthreads();
#pragma unroll
    for (int ii = 0; ii < 2; ++ii) {
        float inv = 1.f / (redB[g * 2][ii] + redB[g * 2 + 1][ii]);
        attQ[g * 2 + ii][j] = p[ii] * inv;
    }

    int w = j, ph = g;
    float pv0 = 0.f, pv1 = 0.f;
#pragma unroll
    for (int it = 0; it < 8; ++it) {
        int idx = tid + it * 512;
        int r = idx >> 7, ww = idx & 127;
        rv[it] = (ww < WW) ? x3T[(b * FF + r) * WW + ww] : 0.f;
    }
    __syncthreads();
#pragma unroll
    for (int it = 0; it < 8; ++it) {
        int idx = tid + it * 512;
        Rs[0][idx >> 7][idx & 127] = rv[it];
    }
    __syncthreads();
    const float* a0 = attQ[ph * 2];
    const float* a1 = attQ[ph * 2 + 1];
    for (int jc = 0; jc < 4; ++jc) {
        int buf = jc & 1;
        if (jc < 3) {
            int r0 = (jc + 1) * 32;
#pragma unroll
            for (int it = 0; it < 8; ++it) {
                int idx = tid + it * 512;
                int r = idx >> 7, ww = idx & 127;
                rv[it] = (ww < WW) ? x3T[(b * FF + r0 + r) * WW + ww] : 0.f;
            }
        }
#pragma unroll 8
        for (int r = 0; r < 32; ++r) {
            float xv = Rs[buf][r][w];
            int row = jc * 32 + r;
            pv0 += a0[row] * xv;
            pv1 += a1[row] * xv;
        }
        if (jc < 3) {
#pragma unroll
            for (int it = 0; it < 8; ++it) {
                int idx = tid + it * 512;
                Rs[buf ^ 1][idx >> 7][idx & 127] = rv[it];
            }
        }
        __syncthreads();
    }
    bool wok = (w < WW);
    float fcv = wok ? fcw[w] : 0.f;
    float tv[2] = {tanhf(pv0) * fcv, tanhf(pv1) * fcv};
#pragma unroll
    for (int off = 32; off > 0; off >>= 1) {
#pragma unroll
        for (int ii = 0; ii < 2; ++ii) tv[ii] += __shfl_xor(tv[ii], off);
    }
    if ((tid & 63) == 0) { redT[wv][0] = tv[0]; redT[wv][1] = tv[1]; }
    __syncthreads();
    if (tid < 8) {
        int q = tid, php = q >> 1, ii = q & 1;
        tj[b * FF + f0 + q] = redT[php * 2][ii] + redT[php * 2 + 1][ii];
    }
}

// K6: out[b,f] = tanh(sum_j cos(f,j)*tj[b,j] + fcb). (R12 version)
__global__ __launch_bounds__(128) void k_fc(const float* __restrict__ tjg,
                                            const float* __restrict__ emb,
                                            const float* __restrict__ fcb,
                                            float* __restrict__ out) {
    int b = blockIdx.x;
    int f = threadIdx.x;
    __shared__ float en[FF][12];
    __shared__ float tjs[FF];
    {
        float4 e0 = *(const float4*)&emb[f * 8];
        float4 e1 = *(const float4*)&emb[f * 8 + 4];
        float n = e0.x*e0.x + e0.y*e0.y + e0.z*e0.z + e0.w*e0.w +
                  e1.x*e1.x + e1.y*e1.y + e1.z*e1.z + e1.w*e1.w;
        float rin = rsqrtf(n);
        float4 a = make_float4(e0.x*rin, e0.y*rin, e0.z*rin, e0.w*rin);
        float4 c = make_float4(e1.x*rin, e1.y*rin, e1.z*rin, e1.w*rin);
        *(float4*)&en[f][0] = a;
        *(float4*)&en[f][4] = c;
        tjs[f] = tjg[b * FF + f];
    }
    __syncthreads();
    float er[8];
#pragma unroll
    for (int k = 0; k < 8; ++k) er[k] = en[f][k];
    float acc = fcb[0];
    for (int jj = 0; jj < FF; ++jj) {
        float4 a = *(const float4*)&en[jj][0];
        float4 c = *(const float4*)&en[jj][4];
        float d8 = er[0]*a.x + er[1]*a.y + er[2]*a.z + er[3]*a.w +
                   er[4]*c.x + er[5]*c.y + er[6]*c.z + er[7]*c.w;
        acc += d8 * tjs[jj];
    }
    out[b * FF + f] = tanhf(acc);
}

extern "C" void kernel_launch(void* const* d_in, const int* in_sizes, int n_in,
                              void* d_out, int out_size, void* d_ws, size_t ws_size,
                              hipStream_t stream) {
    const float* x     = (const float*)d_in[0];
    const float* cw    = (const float*)d_in[1];
    const float* cb    = (const float*)d_in[2];
    const float* tlw   = (const float*)d_in[3];
    const float* tlb   = (const float*)d_in[4];
    const float* ta    = (const float*)d_in[5];
    const float* tbias = (const float*)d_in[6];
    const float* flw   = (const float*)d_in[7];
    const float* flb   = (const float*)d_in[8];
    const float* fa    = (const float*)d_in[9];
    const float* fbias = (const float*)d_in[10];
    const float* emb   = (const float*)d_in[11];
    const float* fcw   = (const float*)d_in[12];
    const float* fcb   = (const float*)d_in[13];
    float* out = (float*)d_out;
    float* ws = (float*)d_ws;

    float* x2   = ws + 409600;
    float* x3T  = ws + 819200;
    float* LT   = ws + 1228800;   // reused as LfT
    float* Rt   = ws + 2048000;   // reused as RfT
    float* tj   = ws + 2867200;
    float* wt   = ws + 3297280;
    float* tlwT = ws + 3411968;
    float* flwT = ws + 3477504;

    k_prep<<<448, 256, 0, stream>>>(cw, tlw, flw, wt, tlwT, flwT);
    k_conv<<<BB * 10, 512, 0, stream>>>(x, wt, cb, x2);
    k_lr_t<<<BB * 13, 512, 0, stream>>>(x2, tlwT, tlb, LT, Rt);
    k_att_t<<<BB * 13, 512, 0, stream>>>(LT, Rt, ta, tbias, x2, x3T);
    k_lr_f<<<BB * 16, 512, 0, stream>>>(x3T, flwT, flb, LT, Rt);
    k_att_f<<<BB * 16, 512, 0, stream>>>(LT, Rt, fa, fbias, x3T, fcw, tj);
    k_fc<<<BB, 128, 0, stream>>>(tj, emb, fcb, out);
}

// Round 18
// 118.193 us; speedup vs baseline: 1.1015x; 1.0928x over previous
//
#include <hip/hip_runtime.h>
#include <math.h>

#define BB 32
#define WW 100
#define FF 128
#define KS 7
#define ET 256   // 2F (temporal GAT embed)
#define EF 200   // 2W (feature GAT embed)

// b = blockIdx & 31 (b-minor): BB=32 ≡ 0 mod 8 XCDs -> all tiles of batch b
// land on one XCD; per-b panels are HBM-fetched once, then L2-served.

// K0: transpose the three weight tensors
__global__ void k_prep(const float* __restrict__ cw, const float* __restrict__ tlw,
                       const float* __restrict__ flw, float* __restrict__ wt,
                       float* __restrict__ tlwT, float* __restrict__ flwT) {
    int id = blockIdx.x * 256 + threadIdx.x;
    if (id < KS * FF * FF) {
        int o = id & (FF - 1);
        int r = id >> 7;
        int k = r % KS;
        int i = r / KS;
        wt[id] = cw[(o * FF + i) * KS + k];
    }
    if (id < ET * ET) {
        int e = id & (ET - 1);
        int d = id >> 8;
        tlwT[id] = tlw[e * ET + d];
    }
    if (id < EF * EF) {
        int e = id % EF;
        int d = id / EF;
        flwT[id] = flw[e * EF + d];
    }
}

// K1: Conv1d 'same' + relu, pos-encode fused into staging.
#define CTW 10
#define NROW 16
#define XPAD 20
__global__ __launch_bounds__(512) void k_conv(const float* __restrict__ x,
                                              const float* __restrict__ wt,
                                              const float* __restrict__ cb,
                                              float* __restrict__ x2) {
    int b = blockIdx.x & 31;
    int tile = blockIdx.x >> 5;
    int w0 = tile * CTW;
    int tid = threadIdx.x;
    int o = tid & (FF - 1);
    int h = tid >> 7;
    __shared__ float xs[FF][XPAD];
    __shared__ float part[4][CTW][FF];
    for (int idx = tid; idx < NROW * FF; idx += 512) {
        int r = idx >> 7, f = idx & (FF - 1);
        int t = w0 - 3 + r;
        float v = 0.f;
        if ((unsigned)t < WW) {
            float div = __expf((float)f * (-9.210340371976184f / (float)FF));
            float arg = (float)t * div;
            v = x[(b * WW + t) * FF + f] + __sinf(arg) + __cosf(arg);
        }
        xs[f][r] = v;
    }
    __syncthreads();
    float acc[CTW];
#pragma unroll
    for (int t = 0; t < CTW; ++t) acc[t] = 0.f;
    const float* wbase = wt + (h * 32) * KS * FF + o;
#pragma unroll 2
    for (int il = 0; il < 32; ++il) {
        int i = h * 32 + il;
        float4 X0 = *(const float4*)&xs[i][0];
        float4 X1 = *(const float4*)&xs[i][4];
        float4 X2 = *(const float4*)&xs[i][8];
        float4 X3 = *(const float4*)&xs[i][12];
        float xr[16] = {X0.x, X0.y, X0.z, X0.w, X1.x, X1.y, X1.z, X1.w,
                        X2.x, X2.y, X2.z, X2.w, X3.x, X3.y, X3.z, X3.w};
        const float* wp = wbase + il * KS * FF;
#pragma unroll
        for (int k = 0; k < KS; ++k) {
            float wv = wp[k * FF];
#pragma unroll
            for (int t = 0; t < CTW; ++t) acc[t] += xr[t + k] * wv;
        }
    }
#pragma unroll
    for (int t = 0; t < CTW; ++t) part[h][t][o] = acc[t];
    __syncthreads();
    for (int idx = tid; idx < CTW * FF; idx += 512) {
        int t = idx >> 7, oo = idx & (FF - 1);
        float s = part[0][t][oo] + part[1][t][oo] + part[2][t][oo] +
                  part[3][t][oo] + cb[oo];
        x2[(b * WW + w0 + t) * FF + oo] = fmaxf(s, 0.f);
    }
}

// K2: temporal L/R GEMM. Outputs TRANSPOSED: LT/Rt (B,256,100).
__global__ __launch_bounds__(512) void k_lr_t(const float* __restrict__ x2,
                                              const float* __restrict__ tlwT,
                                              const float* __restrict__ tlb,
                                              float* __restrict__ LT,
                                              float* __restrict__ Rt) {
    int b = blockIdx.x & 31;
    int tile = blockIdx.x >> 5;
    int i0 = tile * 8;
    int tid = threadIdx.x;
    int e = tid & 255;
    int rh = tid >> 8;
    __shared__ float xs[8][FF];
    for (int idx = tid; idx < 8 * FF; idx += 512) {
        int r = idx >> 7, d = idx & (FF - 1);
        int row = i0 + r; if (row >= WW) row = WW - 1;
        xs[r][d] = x2[(b * WW + row) * FF + d];
    }
    __syncthreads();
    float aL[4] = {0, 0, 0, 0}, aR[4] = {0, 0, 0, 0};
    const float* wl = tlwT + e;
#pragma unroll 2
    for (int dc = 0; dc < 32; ++dc) {
        float xv[4][4];
#pragma unroll
        for (int r = 0; r < 4; ++r)
            *(float4*)xv[r] = *(const float4*)&xs[rh * 4 + r][dc * 4];
#pragma unroll
        for (int q = 0; q < 4; ++q) {
            int d = dc * 4 + q;
            float wL = wl[d * ET];
            float wR = wl[(FF + d) * ET];
#pragma unroll
            for (int r = 0; r < 4; ++r) {
                aL[r] += xv[r][q] * wL;
                aR[r] += xv[r][q] * wR;
            }
        }
    }
    int ibase = i0 + rh * 4;
    if (ibase < WW) {
        float lb = tlb[e];
        float o0[4];
#pragma unroll
        for (int r = 0; r < 4; ++r) o0[r] = aL[r] + lb;
        *(float4*)&LT[(b * ET + e) * WW + ibase] = *(float4*)o0;
        *(float4*)&Rt[(b * ET + e) * WW + ibase] = *(float4*)aR;
    }
}

// K3: temporal attention. QT=8, 512 thr, double-buffered async staging.
__global__ __launch_bounds__(512) void k_att_t(const float* __restrict__ LT,
                                               const float* __restrict__ Rt,
                                               const float* __restrict__ ta,
                                               const float* __restrict__ tbias,
                                               const float* __restrict__ x2,
                                               float* __restrict__ x3T) {
    int b = blockIdx.x & 31;
    int tile = blockIdx.x >> 5;   // 0..12
    int i0 = tile * 8;
    int tid = threadIdx.x;
    int j = tid & 127, g = tid >> 7;
    __shared__ float Rs[2][32][FF];   // 32KB double buffer; reused for x2 in PV
    __shared__ float Ls[2][32][8];
    __shared__ float tas[ET];
    __shared__ float attQ[8][FF];     // [query][j]; rows >= WW hold 0
    __shared__ float ob[8][FF];
    __shared__ float redA[8][2], redB[8][2];
    if (tid < ET) tas[tid] = ta[tid];

    float rv[8];
    float lvr = 0.f;
    // stage chunk 0
    {
        const float* Rb = Rt + (b * ET) * WW;
#pragma unroll
        for (int it = 0; it < 8; ++it) {
            int idx = tid + it * 512;
            int er = idx >> 7, w = idx & 127;
            rv[it] = (w < WW) ? Rb[er * WW + w] : 0.f;
        }
        if (tid < 256) {
            int er = tid >> 3, qq = tid & 7;
            int row = i0 + qq; if (row >= WW) row = WW - 1;
            lvr = LT[(b * ET + er) * WW + row];
        }
    }
#pragma unroll
    for (int it = 0; it < 8; ++it) {
        int idx = tid + it * 512;
        Rs[0][idx >> 7][idx & 127] = rv[it];
    }
    if (tid < 256) Ls[0][tid >> 3][tid & 7] = lvr;
    __syncthreads();

    float s0 = 0.f, s1 = 0.f;
    for (int ch = 0; ch < 8; ++ch) {
        int buf = ch & 1;
        if (ch < 7) {               // issue next-chunk loads BEFORE compute
            int e0 = (ch + 1) * 32;
            const float* Rb = Rt + (b * ET + e0) * WW;
#pragma unroll
            for (int it = 0; it < 8; ++it) {
                int idx = tid + it * 512;
                int er = idx >> 7, w = idx & 127;
                rv[it] = (w < WW) ? Rb[er * WW + w] : 0.f;
            }
            if (tid < 256) {
                int er = tid >> 3, qq = tid & 7;
                int row = i0 + qq; if (row >= WW) row = WW - 1;
                lvr = LT[(b * ET + e0 + er) * WW + row];
            }
        }
        int e0 = ch * 32;
#pragma unroll 8
        for (int e = 0; e < 32; ++e) {
            float rj = Rs[buf][e][j];
            float ae = tas[e0 + e];
            float2 lv2 = *(const float2*)&Ls[buf][e][g * 2];
            float v;
            v = lv2.x + rj; v = fmaxf(v, 0.2f * v); s0 += v * ae;
            v = lv2.y + rj; v = fmaxf(v, 0.2f * v); s1 += v * ae;
        }
        if (ch < 7) {               // write into the other buffer
#pragma unroll
            for (int it = 0; it < 8; ++it) {
                int idx = tid + it * 512;
                Rs[buf ^ 1][idx >> 7][idx & 127] = rv[it];
            }
            if (tid < 256) Ls[buf ^ 1][tid >> 3][tid & 7] = lvr;
        }
        __syncthreads();            // single barrier per chunk
    }

    // softmax
    float ej[2];
    {
        int iq = i0 + g * 2;
        float bv0 = (j < WW && iq < WW) ? tbias[iq * WW + j] : 0.f;
        float bv1 = (j < WW && iq + 1 < WW) ? tbias[(iq + 1) * WW + j] : 0.f;
        ej[0] = (j < WW && iq < WW) ? s0 + bv0 : -1e30f;
        ej[1] = (j < WW && iq + 1 < WW) ? s1 + bv1 : -1e30f;
    }
    float m[2] = {ej[0], ej[1]};
#pragma unroll
    for (int off = 32; off > 0; off >>= 1) {
#pragma unroll
        for (int ii = 0; ii < 2; ++ii) m[ii] = fmaxf(m[ii], __shfl_xor(m[ii], off));
    }
    int wv = tid >> 6;
    if ((tid & 63) == 0) { redA[wv][0] = m[0]; redA[wv][1] = m[1]; }
    __syncthreads();
    float p[2], ps[2];
#pragma unroll
    for (int ii = 0; ii < 2; ++ii) {
        float mx = fmaxf(redA[g * 2][ii], redA[g * 2 + 1][ii]);
        p[ii] = (j < WW) ? __expf(ej[ii] - mx) : 0.f;
        ps[ii] = p[ii];
    }
#pragma unroll
    for (int off = 32; off > 0; off >>= 1) {
#pragma unroll
        for (int ii = 0; ii < 2; ++ii) ps[ii] += __shfl_xor(ps[ii], off);
    }
    if ((tid & 63) == 0) { redB[wv][0] = ps[0]; redB[wv][1] = ps[1]; }
    __syncthreads();
#pragma unroll
    for (int ii = 0; ii < 2; ++ii) {
        float inv = 1.f / (redB[g * 2][ii] + redB[g * 2 + 1][ii]);
        attQ[g * 2 + ii][j] = p[ii] * inv;   // p==0 for j>=WW -> rows zeroed
    }

    // PV: 4 chunks of 32 rows, double-buffered in the same Rs buffers.
    int d = j, ph = g;
    float pv0 = 0.f, pv1 = 0.f;
#pragma unroll
    for (int it = 0; it < 8; ++it) {       // stage PV chunk 0 (rows 0..31)
        int idx = tid + it * 512;
        int r = idx >> 7, f = idx & 127;
        rv[it] = (r < WW) ? x2[(b * WW + r) * FF + f] : 0.f;
    }
    __syncthreads();                        // score reads done
#pragma unroll
    for (int it = 0; it < 8; ++it) {
        int idx = tid + it * 512;
        Rs[0][idx >> 7][idx & 127] = rv[it];
    }
    __syncthreads();                        // attQ writes + chunk0 writes visible
    const float* a0 = attQ[ph * 2];
    const float* a1 = attQ[ph * 2 + 1];
    for (int jc = 0; jc < 4; ++jc) {
        int buf = jc & 1;
        if (jc < 3) {
            int r0 = (jc + 1) * 32;
#pragma unroll
            for (int it = 0; it < 8; ++it) {
                int idx = tid + it * 512;
                int r = idx >> 7, f = idx & 127;
                int row = r0 + r;
                rv[it] = (row < WW) ? x2[(b * WW + row) * FF + f] : 0.f;
            }
        }
#pragma unroll 8
        for (int r = 0; r < 32; ++r) {
            float xv = Rs[buf][r][d];
            int row = jc * 32 + r;
            pv0 += a0[row] * xv;
            pv1 += a1[row] * xv;
        }
        if (jc < 3) {
#pragma unroll
            for (int it = 0; it < 8; ++it) {
                int idx = tid + it * 512;
                Rs[buf ^ 1][idx >> 7][idx & 127] = rv[it];
            }
        }
        __syncthreads();
    }
    ob[ph * 2][d] = tanhf(pv0);
    ob[ph * 2 + 1][d] = tanhf(pv1);
    __syncthreads();
    if (tid < 256) {
        int f = tid >> 1, half = tid & 1;
        if (i0 + half * 4 < WW) {
            float4 v = make_float4(ob[half * 4][f], ob[half * 4 + 1][f],
                                   ob[half * 4 + 2][f], ob[half * 4 + 3][f]);
            *(float4*)&x3T[(b * FF + f) * WW + i0 + half * 4] = v;
        }
    }
}

// K4: feature L/R GEMM. LfT/RfT (B,200,128) transposed.
__global__ __launch_bounds__(512) void k_lr_f(const float* __restrict__ x3T,
                                              const float* __restrict__ flwT,
                                              const float* __restrict__ flb,
                                              float* __restrict__ LfT,
                                              float* __restrict__ RfT) {
    int b = blockIdx.x & 31;
    int tile = blockIdx.x >> 5;
    int f0 = tile * 8;
    int tid = threadIdx.x;
    int e = tid & 255;
    int rh = tid >> 8;
    __shared__ float xs[8][WW];
    for (int idx = tid; idx < 8 * WW; idx += 512) {
        int r = idx / WW, d = idx % WW;
        xs[r][d] = x3T[(b * FF + f0 + r) * WW + d];
    }
    __syncthreads();
    if (e < EF) {
        float aL[4] = {0, 0, 0, 0}, aR[4] = {0, 0, 0, 0};
        const float* wl = flwT + e;
#pragma unroll 2
        for (int dc = 0; dc < 25; ++dc) {
            float xv[4][4];
#pragma unroll
            for (int r = 0; r < 4; ++r)
                *(float4*)xv[r] = *(const float4*)&xs[rh * 4 + r][dc * 4];
#pragma unroll
            for (int q = 0; q < 4; ++q) {
                int d = dc * 4 + q;
                float wL = wl[d * EF];
                float wR = wl[(WW + d) * EF];
#pragma unroll
                for (int r = 0; r < 4; ++r) {
                    aL[r] += xv[r][q] * wL;
                    aR[r] += xv[r][q] * wR;
                }
            }
        }
        float lb = flb[e];
        float o0[4];
#pragma unroll
        for (int r = 0; r < 4; ++r) o0[r] = aL[r] + lb;
        int fbase = f0 + rh * 4;
        *(float4*)&LfT[(b * EF + e) * FF + fbase] = *(float4*)o0;
        *(float4*)&RfT[(b * EF + e) * FF + fbase] = *(float4*)aR;
    }
}

// K5: feature attention. QT=8, 512 thr, double-buffered; fused tj reduction.
__global__ __launch_bounds__(512) void k_att_f(const float* __restrict__ LfT,
                                               const float* __restrict__ RfT,
                                               const float* __restrict__ fa,
                                               const float* __restrict__ fbias,
                                               const float* __restrict__ x3T,
                                               const float* __restrict__ fcw,
                                               float* __restrict__ tj) {
    int b = blockIdx.x & 31;
    int tile = blockIdx.x >> 5;   // 0..15
    int f0 = tile * 8;
    int tid = threadIdx.x;
    int j = tid & 127, g = tid >> 7;
    __shared__ float Rs[2][40][FF];   // 40KB double buffer; PV uses 32 rows
    __shared__ float Ls[2][40][8];
    __shared__ float fas[EF];
    __shared__ float attQ[8][FF];
    __shared__ float redA[8][2], redB[8][2], redT[8][2];
    if (tid < EF) fas[tid] = fa[tid];

    float rv[10];
    float lvr = 0.f;
    {
        const float* Rb = RfT + (b * EF) * FF;
#pragma unroll
        for (int it = 0; it < 10; ++it) {
            int idx = tid + it * 512;
            rv[it] = Rb[idx];      // 40*128 = 5120 exact, row-major contiguous
        }
        if (tid < 320) {
            int er = tid >> 3, qq = tid & 7;
            lvr = LfT[(b * EF + er) * FF + f0 + qq];
        }
    }
#pragma unroll
    for (int it = 0; it < 10; ++it) {
        int idx = tid + it * 512;
        Rs[0][idx >> 7][idx & 127] = rv[it];
    }
    if (tid < 320) Ls[0][tid >> 3][tid & 7] = lvr;
    __syncthreads();

    float s0 = 0.f, s1 = 0.f;
    for (int ch = 0; ch < 5; ++ch) {
        int buf = ch & 1;
        if (ch < 4) {
            int e0 = (ch + 1) * 40;
            const float* Rb = RfT + (b * EF + e0) * FF;
#pragma unroll
            for (int it = 0; it < 10; ++it) {
                int idx = tid + it * 512;
                rv[it] = Rb[idx];
            }
            if (tid < 320) {
                int er = tid >> 3, qq = tid & 7;
                lvr = LfT[(b * EF + e0 + er) * FF + f0 + qq];
            }
        }
        int e0 = ch * 40;
#pragma unroll 8
        for (int e = 0; e < 40; ++e) {
            float rj = Rs[buf][e][j];
            float ae = fas[e0 + e];
            float2 lv2 = *(const float2*)&Ls[buf][e][g * 2];
            float v;
            v = lv2.x + rj; v = fmaxf(v, 0.2f * v); s0 += v * ae;
            v = lv2.y + rj; v = fmaxf(v, 0.2f * v); s1 += v * ae;
        }
        if (ch < 4) {
#pragma unroll
            for (int it = 0; it < 10; ++it) {
                int idx = tid + it * 512;
                Rs[buf ^ 1][idx >> 7][idx & 127] = rv[it];
            }
            if (tid < 320) Ls[buf ^ 1][tid >> 3][tid & 7] = lvr;
        }
        __syncthreads();
    }

    float ej[2] = {s0 + fbias[(f0 + g * 2) * FF + j],
                   s1 + fbias[(f0 + g * 2 + 1) * FF + j]};
    float m[2] = {ej[0], ej[1]};
#pragma unroll
    for (int off = 32; off > 0; off >>= 1) {
#pragma unroll
        for (int ii = 0; ii < 2; ++ii) m[ii] = fmaxf(m[ii], __shfl_xor(m[ii], off));
    }
    int wv = tid >> 6;
    if ((tid & 63) == 0) { redA[wv][0] = m[0]; redA[wv][1] = m[1]; }
    __syncthreads();
    float p[2], ps[2];
#pragma unroll
    for (int ii = 0; ii < 2; ++ii) {
        float mx = fmaxf(redA[g * 2][ii], redA[g * 2 + 1][ii]);
        p[ii] = __expf(ej[ii] - mx);
        ps[ii] = p[ii];
    }
#pragma unroll
    for (int off = 32; off > 0; off >>= 1) {
#pragma unroll
        for (int ii = 0; ii < 2; ++ii) ps[ii] += __shfl_xor(ps[ii], off);
    }
    if ((tid & 63) == 0) { redB[wv][0] = ps[0]; redB[wv][1] = ps[1]; }
    __syncthreads();
#pragma unroll
    for (int ii = 0; ii < 2; ++ii) {
        float inv = 1.f / (redB[g * 2][ii] + redB[g * 2 + 1][ii]);
        attQ[g * 2 + ii][j] = p[ii] * inv;
    }

    // PV: 4 chunks of 32 rows (128 exact), double-buffered in Rs.
    int w = j, ph = g;
    float pv0 = 0.f, pv1 = 0.f;
#pragma unroll
    for (int it = 0; it < 8; ++it) {
        int idx = tid + it * 512;
        int r = idx >> 7, ww = idx & 127;
        rv[it] = (ww < WW) ? x3T[(b * FF + r) * WW + ww] : 0.f;
    }
    __syncthreads();
#pragma unroll
    for (int it = 0; it < 8; ++it) {
        int idx = tid + it * 512;
        Rs[0][idx >> 7][idx & 127] = rv[it];
    }
    __syncthreads();
    const float* a0 = attQ[ph * 2];
    const float* a1 = attQ[ph * 2 + 1];
    for (int jc = 0; jc < 4; ++jc) {
        int buf = jc & 1;
        if (jc < 3) {
            int r0 = (jc + 1) * 32;
#pragma unroll
            for (int it = 0; it < 8; ++it) {
                int idx = tid + it * 512;
                int r = idx >> 7, ww = idx & 127;
                rv[it] = (ww < WW) ? x3T[(b * FF + r0 + r) * WW + ww] : 0.f;
            }
        }
#pragma unroll 8
        for (int r = 0; r < 32; ++r) {
            float xv = Rs[buf][r][w];
            int row = jc * 32 + r;
            pv0 += a0[row] * xv;
            pv1 += a1[row] * xv;
        }
        if (jc < 3) {
#pragma unroll
            for (int it = 0; it < 8; ++it) {
                int idx = tid + it * 512;
                Rs[buf ^ 1][idx >> 7][idx & 127] = rv[it];
            }
        }
        __syncthreads();
    }
    bool wok = (w < WW);
    float fcv = wok ? fcw[w] : 0.f;
    float tv[2] = {tanhf(pv0) * fcv, tanhf(pv1) * fcv};
#pragma unroll
    for (int off = 32; off > 0; off >>= 1) {
#pragma unroll
        for (int ii = 0; ii < 2; ++ii) tv[ii] += __shfl_xor(tv[ii], off);
    }
    if ((tid & 63) == 0) { redT[wv][0] = tv[0]; redT[wv][1] = tv[1]; }
    __syncthreads();
    if (tid < 8) {
        int q = tid, php = q >> 1, ii = q & 1;
        tj[b * FF + f0 + q] = redT[php * 2][ii] + redT[php * 2 + 1][ii];
    }
}

// K6: out[b,f] = tanh(sum_j cos(f,j)*tj[b,j] + fcb). cos from normalized emb.
__global__ __launch_bounds__(128) void k_fc(const float* __restrict__ tjg,
                                            const float* __restrict__ emb,
                                            const float* __restrict__ fcb,
                                            float* __restrict__ out) {
    int b = blockIdx.x;
    int f = threadIdx.x;
    __shared__ float en[FF][12];
    __shared__ float tjs[FF];
    {
        float4 e0 = *(const float4*)&emb[f * 8];
        float4 e1 = *(const float4*)&emb[f * 8 + 4];
        float n = e0.x*e0.x + e0.y*e0.y + e0.z*e0.z + e0.w*e0.w +
                  e1.x*e1.x + e1.y*e1.y + e1.z*e1.z + e1.w*e1.w;
        float rin = rsqrtf(n);
        float4 a = make_float4(e0.x*rin, e0.y*rin, e0.z*rin, e0.w*rin);
        float4 c = make_float4(e1.x*rin, e1.y*rin, e1.z*rin, e1.w*rin);
        *(float4*)&en[f][0] = a;
        *(float4*)&en[f][4] = c;
        tjs[f] = tjg[b * FF + f];
    }
    __syncthreads();
    float er[8];
#pragma unroll
    for (int k = 0; k < 8; ++k) er[k] = en[f][k];
    float acc = fcb[0];
    for (int jj = 0; jj < FF; ++jj) {
        float4 a = *(const float4*)&en[jj][0];
        float4 c = *(const float4*)&en[jj][4];
        float d8 = er[0]*a.x + er[1]*a.y + er[2]*a.z + er[3]*a.w +
                   er[4]*c.x + er[5]*c.y + er[6]*c.z + er[7]*c.w;
        acc += d8 * tjs[jj];
    }
    out[b * FF + f] = tanhf(acc);
}

extern "C" void kernel_launch(void* const* d_in, const int* in_sizes, int n_in,
                              void* d_out, int out_size, void* d_ws, size_t ws_size,
                              hipStream_t stream) {
    const float* x     = (const float*)d_in[0];
    const float* cw    = (const float*)d_in[1];
    const float* cb    = (const float*)d_in[2];
    const float* tlw   = (const float*)d_in[3];
    const float* tlb   = (const float*)d_in[4];
    const float* ta    = (const float*)d_in[5];
    const float* tbias = (const float*)d_in[6];
    const float* flw   = (const float*)d_in[7];
    const float* flb   = (const float*)d_in[8];
    const float* fa    = (const float*)d_in[9];
    const float* fbias = (const float*)d_in[10];
    const float* emb   = (const float*)d_in[11];
    const float* fcw   = (const float*)d_in[12];
    const float* fcb   = (const float*)d_in[13];
    float* out = (float*)d_out;
    float* ws = (float*)d_ws;

    float* x2   = ws + 409600;
    float* x3T  = ws + 819200;
    float* LT   = ws + 1228800;   // reused as LfT
    float* Rt   = ws + 2048000;   // reused as RfT
    float* tj   = ws + 2867200;
    float* wt   = ws + 3297280;
    float* tlwT = ws + 3411968;
    float* flwT = ws + 3477504;

    k_prep<<<448, 256, 0, stream>>>(cw, tlw, flw, wt, tlwT, flwT);
    k_conv<<<BB * 10, 512, 0, stream>>>(x, wt, cb, x2);
    k_lr_t<<<BB * 13, 512, 0, stream>>>(x2, tlwT, tlb, LT, Rt);
    k_att_t<<<BB * 13, 512, 0, stream>>>(LT, Rt, ta, tbias, x2, x3T);
    k_lr_f<<<BB * 16, 512, 0, stream>>>(x3T, flwT, flb, LT, Rt);
    k_att_f<<<BB * 16, 512, 0, stream>>>(LT, Rt, fa, fbias, x3T, fcw, tj);
    k_fc<<<BB, 128, 0, stream>>>(tj, emb, fcb, out);
}